// Round 2
// baseline (671.893 us; speedup 1.0000x reference)
//
#include <hip/hip_runtime.h>
#include <hip/hip_bf16.h>

#define HDIM 1024
#define SEQ  2048
#define BATCH 32
#define M_TOTAL (BATCH * SEQ)   // 65536
#define BM 256
#define BN 128
#define BK 32
#define NSLICE 16               // (HDIM/BN) * 2 wave-pairs

typedef __bf16 bf16x8 __attribute__((ext_vector_type(8)));
typedef float  f32x4  __attribute__((ext_vector_type(4)));
typedef unsigned short u16;
#define AS1 __attribute__((address_space(1)))
#define AS3 __attribute__((address_space(3)))

__device__ __forceinline__ u16 f2bf(float f) {
    unsigned int u = __float_as_uint(f);
    u += 0x7FFFu + ((u >> 16) & 1u);   // round-to-nearest-even
    return (u16)(u >> 16);
}

// ---- fp32 -> bf16, 8 elems/thread ----
__global__ __launch_bounds__(256) void cvt_kernel(const float* __restrict__ in,
                                                  u16* __restrict__ out) {
    size_t i = ((size_t)blockIdx.x * 256 + threadIdx.x) * 8;
    float4 f0 = *(const float4*)(in + i);
    float4 f1 = *(const float4*)(in + i + 4);
    uint4 v;
    v.x = (unsigned)f2bf(f0.x) | ((unsigned)f2bf(f0.y) << 16);
    v.y = (unsigned)f2bf(f0.z) | ((unsigned)f2bf(f0.w) << 16);
    v.z = (unsigned)f2bf(f1.x) | ((unsigned)f2bf(f1.y) << 16);
    v.w = (unsigned)f2bf(f1.z) | ((unsigned)f2bf(f1.w) << 16);
    *(uint4*)(out + i) = v;
}

// ---- qb[b][o] = query[b]·Wa_w[o] + Wa_b[o] + Ua_b[o] (fp32) ----
__global__ __launch_bounds__(256) void qb_kernel(const float* __restrict__ query,
                                                 const float* __restrict__ Wa_w,
                                                 const float* __restrict__ Wa_b,
                                                 const float* __restrict__ Ua_b,
                                                 float* __restrict__ qb) {
    __shared__ float qs[HDIM];
    const int b = blockIdx.x;
    const int tid = threadIdx.x;
    ((float4*)qs)[tid] = ((const float4*)(query + b * HDIM))[tid];
    __syncthreads();
    const int lane = tid & 63;
    const int w = tid >> 6;
    const int obase = blockIdx.y * 64 + w * 16;
    for (int i = 0; i < 16; i++) {
        int o = obase + i;
        const float4* wrow = (const float4*)(Wa_w + (size_t)o * HDIM);
        float s = 0.f;
        #pragma unroll
        for (int j = 0; j < 4; j++) {
            float4 wv = wrow[j * 64 + lane];
            float4 qv = ((const float4*)qs)[j * 64 + lane];
            s += wv.x * qv.x + wv.y * qv.y + wv.z * qv.z + wv.w * qv.w;
        }
        #pragma unroll
        for (int m = 1; m < 64; m <<= 1) s += __shfl_xor(s, m);
        if (lane == 0) qb[b * HDIM + o] = s + Wa_b[o] + Ua_b[o];
    }
}

// ---- GEMM keys·Ua^T + fused tanh + Va dot -> deterministic score slices ----
// grid (M_TOTAL/BM, HDIM/BN) m-major, block 256 (4 waves, each 128x64 tile)
__global__ __launch_bounds__(256, 2) void gemm_score_kernel(const u16* __restrict__ keysb,
                                                            const u16* __restrict__ uab,
                                                            const float* __restrict__ qb,
                                                            const float* __restrict__ vaw,
                                                            float* __restrict__ sp) {
    __shared__ __align__(16) u16 As[BM * BK];   // 16 KB
    __shared__ __align__(16) u16 Bs[BN * BK];   //  8 KB
    const int tid  = threadIdx.x;
    const int lane = tid & 63;
    const int w    = tid >> 6;
    const int m0 = blockIdx.x * BM;
    const int n0 = blockIdx.y * BN;
    const int wave_m = (w & 1) * 128;
    const int wave_n = (w >> 1) * 64;

    f32x4 acc[8][4] = {};

    const int srow = lane >> 2;
    const int scol = (lane & 3) * 8;
    const u16* gA = keysb + (size_t)(m0 + w * 64 + srow) * HDIM + scol;
    const u16* gB = uab   + (size_t)(n0 + w * 32 + srow) * HDIM + scol;
    u16* lA = As + (w * 64) * BK;   // wave-uniform bases
    u16* lB = Bs + (w * 32) * BK;

    const int fr = lane & 15;
    const int fq = lane >> 4;

    for (int k0 = 0; k0 < HDIM; k0 += BK) {
        __syncthreads();
        #pragma unroll
        for (int i = 0; i < 4; i++)
            __builtin_amdgcn_global_load_lds((AS1 void*)(gA + k0 + i * 16 * HDIM),
                                             (AS3 void*)(lA + i * 16 * BK), 16, 0, 0);
        #pragma unroll
        for (int i = 0; i < 2; i++)
            __builtin_amdgcn_global_load_lds((AS1 void*)(gB + k0 + i * 16 * HDIM),
                                             (AS3 void*)(lB + i * 16 * BK), 16, 0, 0);
        __syncthreads();

        bf16x8 a[8], b[4];
        #pragma unroll
        for (int i = 0; i < 8; i++)
            a[i] = *(const bf16x8*)(As + (wave_m + i * 16 + fr) * BK + fq * 8);
        #pragma unroll
        for (int i = 0; i < 4; i++)
            b[i] = *(const bf16x8*)(Bs + (wave_n + i * 16 + fr) * BK + fq * 8);
        #pragma unroll
        for (int mi = 0; mi < 8; mi++)
            #pragma unroll
            for (int ni = 0; ni < 4; ni++)
                acc[mi][ni] = __builtin_amdgcn_mfma_f32_16x16x32_bf16(a[mi], b[ni], acc[mi][ni], 0, 0, 0);
    }

    // epilogue: partial score over this wave's 64 n-columns -> slice write
    const int bidx = m0 >> 11;   // BM=256 divides SEQ=2048; constant per block
    float qv[4], vv[4];
    #pragma unroll
    for (int ni = 0; ni < 4; ni++) {
        int n_g = n0 + wave_n + ni * 16 + fr;
        qv[ni] = qb[bidx * HDIM + n_g];
        vv[ni] = vaw[n_g];
    }
    const int slice = blockIdx.y * 2 + (w >> 1);
    float* sl = sp + ((size_t)slice * BATCH + bidx) * SEQ;
    #pragma unroll
    for (int mi = 0; mi < 8; mi++) {
        #pragma unroll
        for (int r = 0; r < 4; r++) {
            float p = 0.f;
            #pragma unroll
            for (int ni = 0; ni < 4; ni++) {
                float x = acc[mi][ni][r] + qv[ni];
                float e = __expf(2.f * x);          // tanh = 1 - 2/(e^{2x}+1), NaN-free
                p += (1.f - 2.f / (e + 1.f)) * vv[ni];
            }
            p += __shfl_xor(p, 1);
            p += __shfl_xor(p, 2);
            p += __shfl_xor(p, 4);
            p += __shfl_xor(p, 8);
            if (fr == 0) {
                int s_g = (m0 + wave_m + mi * 16 + fq * 4 + r) & (SEQ - 1);
                sl[s_g] = p;
            }
        }
    }
}

// ---- softmax over SEQ per batch; sums 16 slices; zeroes ctx region ----
__global__ __launch_bounds__(256) void softmax_kernel(const float* __restrict__ sp,
                                                      float* __restrict__ weights,
                                                      float* __restrict__ ctx) {
    __shared__ float red[4];
    const int b = blockIdx.x;
    const int tid = threadIdx.x;
    float4 z = {0.f, 0.f, 0.f, 0.f};
    ((float4*)(ctx + b * HDIM))[tid] = z;       // zero context for atomics
    float v[8];
    float mx = -1e30f;
    #pragma unroll
    for (int i = 0; i < 8; i++) {
        int s = tid + i * 256;
        float a = 0.f;
        #pragma unroll
        for (int j = 0; j < NSLICE; j++) a += sp[((size_t)j * BATCH + b) * SEQ + s];
        v[i] = a;
        mx = fmaxf(mx, a);
    }
    #pragma unroll
    for (int m = 1; m < 64; m <<= 1) mx = fmaxf(mx, __shfl_xor(mx, m));
    if ((tid & 63) == 0) red[tid >> 6] = mx;
    __syncthreads();
    mx = fmaxf(fmaxf(red[0], red[1]), fmaxf(red[2], red[3]));
    float sum = 0.f;
    #pragma unroll
    for (int i = 0; i < 8; i++) { v[i] = __expf(v[i] - mx); sum += v[i]; }
    #pragma unroll
    for (int m = 1; m < 64; m <<= 1) sum += __shfl_xor(sum, m);
    __syncthreads();
    if ((tid & 63) == 0) red[tid >> 6] = sum;
    __syncthreads();
    sum = red[0] + red[1] + red[2] + red[3];
    float inv = 1.f / sum;
    #pragma unroll
    for (int i = 0; i < 8; i++) weights[b * SEQ + tid + i * 256] = v[i] * inv;
}

// ---- context[b][h] = sum_s w[b][s] * keys[b][s][h] (fp32 keys) ----
// grid (BATCH, SEQ/64), block 256; atomic partial sums into pre-zeroed ctx
__global__ __launch_bounds__(256) void context_kernel(const float* __restrict__ keys,
                                                      const float* __restrict__ weights,
                                                      float* __restrict__ ctx) {
    __shared__ float wsm[64];
    const int b = blockIdx.x;
    const int s0 = blockIdx.y * 64;
    const int tid = threadIdx.x;
    if (tid < 64) wsm[tid] = weights[b * SEQ + s0 + tid];
    __syncthreads();
    float ax = 0.f, ay = 0.f, az = 0.f, aw = 0.f;
    const float4* kp = (const float4*)(keys + (size_t)b * SEQ * HDIM + (size_t)s0 * HDIM) + tid;
    #pragma unroll 8
    for (int s = 0; s < 64; s++) {
        float4 kv = kp[s * 256];
        float wv = wsm[s];
        ax += wv * kv.x; ay += wv * kv.y; az += wv * kv.z; aw += wv * kv.w;
    }
    float* o = ctx + b * HDIM + tid * 4;
    atomicAdd(o + 0, ax);
    atomicAdd(o + 1, ay);
    atomicAdd(o + 2, az);
    atomicAdd(o + 3, aw);
}

extern "C" void kernel_launch(void* const* d_in, const int* in_sizes, int n_in,
                              void* d_out, int out_size, void* d_ws, size_t ws_size,
                              hipStream_t stream) {
    const float* query = (const float*)d_in[0];
    const float* keys  = (const float*)d_in[1];
    const float* Wa_w  = (const float*)d_in[2];
    const float* Wa_b  = (const float*)d_in[3];
    const float* Ua_w  = (const float*)d_in[4];
    const float* Ua_b  = (const float*)d_in[5];
    const float* Va_w  = (const float*)d_in[6];
    // Va_b unused: softmax is shift-invariant.
    float* out = (float*)d_out;   // [0, 32768) context, [32768, 98304) weights

    char* ws = (char*)d_ws;
    u16*  keysb = (u16*)ws;                                     // 134217728 B
    u16*  uab   = (u16*)(ws + 134217728);                       //   2097152 B
    float* qb   = (float*)(ws + 134217728 + 2097152);           //    131072 B
    float* sp   = (float*)(ws + 134217728 + 2097152 + 131072);  //   4194304 B

    cvt_kernel<<<(BATCH * SEQ * HDIM) / 2048, 256, 0, stream>>>(keys, keysb);
    cvt_kernel<<<(HDIM * HDIM) / 2048, 256, 0, stream>>>(Ua_w, uab);
    qb_kernel<<<dim3(BATCH, HDIM / 64), 256, 0, stream>>>(query, Wa_w, Wa_b, Ua_b, qb);
    gemm_score_kernel<<<dim3(M_TOTAL / BM, HDIM / BN), 256, 0, stream>>>(keysb, uab, qb, Va_w, sp);
    softmax_kernel<<<BATCH, 256, 0, stream>>>(sp, out + BATCH * HDIM, out);
    context_kernel<<<dim3(BATCH, SEQ / 64), 256, 0, stream>>>(keys, out + BATCH * HDIM, out);
}

// Round 3
// 643.959 us; speedup vs baseline: 1.0434x; 1.0434x over previous
//
#include <hip/hip_runtime.h>
#include <hip/hip_bf16.h>

#define HDIM 1024
#define SEQ  2048
#define BATCH 32
#define M_TOTAL (BATCH * SEQ)   // 65536
#define BM 128
#define BN 128
#define BK 32
#define NSLICE 16               // (HDIM/BN)=8 n-tiles x 2 wave-pairs

typedef __bf16 bf16x8 __attribute__((ext_vector_type(8)));
typedef float  f32x4  __attribute__((ext_vector_type(4)));
typedef unsigned short u16;
#define AS1 __attribute__((address_space(1)))
#define AS3 __attribute__((address_space(3)))

__device__ __forceinline__ u16 f2bf(float f) {
    unsigned int u = __float_as_uint(f);
    u += 0x7FFFu + ((u >> 16) & 1u);   // round-to-nearest-even
    return (u16)(u >> 16);
}

__device__ __forceinline__ bf16x8 cvt8(float4 f0, float4 f1) {
    union { bf16x8 v; __hip_bfloat162 h[4]; } u;
    u.h[0] = __float22bfloat162_rn({f0.x, f0.y});
    u.h[1] = __float22bfloat162_rn({f0.z, f0.w});
    u.h[2] = __float22bfloat162_rn({f1.x, f1.y});
    u.h[3] = __float22bfloat162_rn({f1.z, f1.w});
    return u.v;
}

// ---- fp32 -> bf16 (Ua_w only), 8 elems/thread ----
__global__ __launch_bounds__(256) void cvt_kernel(const float* __restrict__ in,
                                                  u16* __restrict__ out) {
    size_t i = ((size_t)blockIdx.x * 256 + threadIdx.x) * 8;
    float4 f0 = *(const float4*)(in + i);
    float4 f1 = *(const float4*)(in + i + 4);
    uint4 v;
    v.x = (unsigned)f2bf(f0.x) | ((unsigned)f2bf(f0.y) << 16);
    v.y = (unsigned)f2bf(f0.z) | ((unsigned)f2bf(f0.w) << 16);
    v.z = (unsigned)f2bf(f1.x) | ((unsigned)f2bf(f1.y) << 16);
    v.w = (unsigned)f2bf(f1.z) | ((unsigned)f2bf(f1.w) << 16);
    *(uint4*)(out + i) = v;
}

// ---- qb[b][o] = query[b]·Wa_w[o] + Wa_b[o] + Ua_b[o] (fp32) ----
__global__ __launch_bounds__(256) void qb_kernel(const float* __restrict__ query,
                                                 const float* __restrict__ Wa_w,
                                                 const float* __restrict__ Wa_b,
                                                 const float* __restrict__ Ua_b,
                                                 float* __restrict__ qb) {
    __shared__ float qs[HDIM];
    const int b = blockIdx.x;
    const int tid = threadIdx.x;
    ((float4*)qs)[tid] = ((const float4*)(query + b * HDIM))[tid];
    __syncthreads();
    const int lane = tid & 63;
    const int w = tid >> 6;
    const int obase = blockIdx.y * 64 + w * 16;
    for (int i = 0; i < 16; i++) {
        int o = obase + i;
        const float4* wrow = (const float4*)(Wa_w + (size_t)o * HDIM);
        float s = 0.f;
        #pragma unroll
        for (int j = 0; j < 4; j++) {
            float4 wv = wrow[j * 64 + lane];
            float4 qv = ((const float4*)qs)[j * 64 + lane];
            s += wv.x * qv.x + wv.y * qv.y + wv.z * qv.z + wv.w * qv.w;
        }
        #pragma unroll
        for (int m = 1; m < 64; m <<= 1) s += __shfl_xor(s, m);
        if (lane == 0) qb[b * HDIM + o] = s + Wa_b[o] + Ua_b[o];
    }
}

// ---- GEMM keys(fp32)·Ua^T(bf16) + fused tanh + Va dot -> score slices ----
// grid (HDIM/BN, M_TOTAL/BM) n-major, block 256 (4 waves, each 64x64 tile)
__global__ __launch_bounds__(256, 3) void gemm_score_kernel(const float* __restrict__ keys,
                                                            const u16* __restrict__ uab,
                                                            const float* __restrict__ qb,
                                                            const float* __restrict__ vaw,
                                                            float* __restrict__ sp) {
    __shared__ __align__(16) float As[BM * BK];   // 16 KB, fp32, xor-swizzled chunks
    __shared__ __align__(16) u16   Bs[BN * BK];   //  8 KB, bf16, xor-swizzled chunks
    const int tid  = threadIdx.x;
    const int lane = tid & 63;
    const int w    = tid >> 6;
    const int n0 = blockIdx.x * BN;
    const int m0 = blockIdx.y * BM;
    const int wave_m = (w & 1) * 64;
    const int wave_n = (w >> 1) * 64;

    f32x4 acc[4][4] = {};

    // A staging: fp32 rows of 32 k = 8 x 16B chunks; swizzle c' = c ^ (row&7).
    // lane -> row lane>>3, stored chunk lane&7 -> source chunk (lane&7)^((lane>>3)&7)
    const int arow = lane >> 3;
    const int achk = (lane & 7) ^ (arow & 7);
    const float* gA = keys + (size_t)(m0 + w * 32 + arow) * HDIM + achk * 4;
    float* lA = As + (w * 32) * BK;            // wave-uniform base
    // B staging: bf16 rows of 32 k = 4 x 16B chunks; swizzle c' = c ^ ((row>>1)&3).
    const int brow = lane >> 2;
    const int bchk = (lane & 3) ^ ((lane >> 3) & 3);
    const u16* gB = uab + (size_t)(n0 + w * 32 + brow) * HDIM + bchk * 8;
    u16* lB = Bs + (w * 32) * BK;

    const int fr = lane & 15;
    const int fq = lane >> 4;
    const int aswz0 = ((2 * fq + 0) ^ (fr & 7)) * 4;   // fp32 chunk byte-swizzle (in floats)
    const int aswz1 = ((2 * fq + 1) ^ (fr & 7)) * 4;
    const int bswz  = (fq ^ ((fr >> 1) & 3)) * 8;      // bf16 chunk (in elems)

    for (int k0 = 0; k0 < HDIM; k0 += BK) {
        __syncthreads();
        #pragma unroll
        for (int i = 0; i < 4; i++)   // 4 loads x 8 fp32 rows = 32 rows per wave
            __builtin_amdgcn_global_load_lds((AS1 void*)(gA + k0 + i * 8 * HDIM),
                                             (AS3 void*)(lA + i * 8 * BK), 16, 0, 0);
        #pragma unroll
        for (int i = 0; i < 2; i++)   // 2 loads x 16 bf16 rows = 32 rows per wave
            __builtin_amdgcn_global_load_lds((AS1 void*)(gB + k0 + i * 16 * HDIM),
                                             (AS3 void*)(lB + i * 16 * BK), 16, 0, 0);
        __syncthreads();

        bf16x8 a[4], b[4];
        #pragma unroll
        for (int i = 0; i < 4; i++) {
            const float* ar = As + (wave_m + i * 16 + fr) * BK;
            float4 f0 = *(const float4*)(ar + aswz0);
            float4 f1 = *(const float4*)(ar + aswz1);
            a[i] = cvt8(f0, f1);
            b[i] = *(const bf16x8*)(Bs + (wave_n + i * 16 + fr) * BK + bswz);
        }
        #pragma unroll
        for (int mi = 0; mi < 4; mi++)
            #pragma unroll
            for (int ni = 0; ni < 4; ni++)
                acc[mi][ni] = __builtin_amdgcn_mfma_f32_16x16x32_bf16(a[mi], b[ni], acc[mi][ni], 0, 0, 0);
    }

    // epilogue: h = tanh(acc + qb), partial score over 64 n-cols -> slice write
    const int bidx = m0 >> 11;   // BM=128 divides SEQ=2048
    float qv[4], vv[4];
    #pragma unroll
    for (int ni = 0; ni < 4; ni++) {
        int n_g = n0 + wave_n + ni * 16 + fr;
        qv[ni] = qb[bidx * HDIM + n_g];
        vv[ni] = vaw[n_g];
    }
    const int slice = blockIdx.x * 2 + (w >> 1);
    float* sl = sp + ((size_t)slice * BATCH + bidx) * SEQ;
    #pragma unroll
    for (int mi = 0; mi < 4; mi++) {
        #pragma unroll
        for (int r = 0; r < 4; r++) {
            float p = 0.f;
            #pragma unroll
            for (int ni = 0; ni < 4; ni++) {
                float x = acc[mi][ni][r] + qv[ni];
                float e = __expf(2.f * x);          // tanh = 1 - 2/(e^{2x}+1), NaN-free
                p += (1.f - 2.f / (e + 1.f)) * vv[ni];
            }
            p += __shfl_xor(p, 1);
            p += __shfl_xor(p, 2);
            p += __shfl_xor(p, 4);
            p += __shfl_xor(p, 8);
            if (fr == 0) {
                int s_g = (m0 + wave_m + mi * 16 + fq * 4 + r) & (SEQ - 1);
                sl[s_g] = p;
            }
        }
    }
}

// ---- softmax over SEQ per batch; sums 16 slices; zeroes ctx region ----
__global__ __launch_bounds__(256) void softmax_kernel(const float* __restrict__ sp,
                                                      float* __restrict__ weights,
                                                      float* __restrict__ ctx) {
    __shared__ float red[4];
    const int b = blockIdx.x;
    const int tid = threadIdx.x;
    float4 z = {0.f, 0.f, 0.f, 0.f};
    ((float4*)(ctx + b * HDIM))[tid] = z;       // zero context for atomics
    float v[8];
    float mx = -1e30f;
    #pragma unroll
    for (int i = 0; i < 8; i++) {
        int s = tid + i * 256;
        float a = 0.f;
        #pragma unroll
        for (int j = 0; j < NSLICE; j++) a += sp[((size_t)j * BATCH + b) * SEQ + s];
        v[i] = a;
        mx = fmaxf(mx, a);
    }
    #pragma unroll
    for (int m = 1; m < 64; m <<= 1) mx = fmaxf(mx, __shfl_xor(mx, m));
    if ((tid & 63) == 0) red[tid >> 6] = mx;
    __syncthreads();
    mx = fmaxf(fmaxf(red[0], red[1]), fmaxf(red[2], red[3]));
    float sum = 0.f;
    #pragma unroll
    for (int i = 0; i < 8; i++) { v[i] = __expf(v[i] - mx); sum += v[i]; }
    #pragma unroll
    for (int m = 1; m < 64; m <<= 1) sum += __shfl_xor(sum, m);
    __syncthreads();
    if ((tid & 63) == 0) red[tid >> 6] = sum;
    __syncthreads();
    sum = red[0] + red[1] + red[2] + red[3];
    float inv = 1.f / sum;
    #pragma unroll
    for (int i = 0; i < 8; i++) weights[b * SEQ + tid + i * 256] = v[i] * inv;
}

// ---- context[b][h] = sum_s w[b][s] * keys[b][s][h] (fp32 keys) ----
// grid (BATCH, SEQ/64), block 256; atomic partial sums into pre-zeroed ctx
__global__ __launch_bounds__(256) void context_kernel(const float* __restrict__ keys,
                                                      const float* __restrict__ weights,
                                                      float* __restrict__ ctx) {
    __shared__ float wsm[64];
    const int b = blockIdx.x;
    const int s0 = blockIdx.y * 64;
    const int tid = threadIdx.x;
    if (tid < 64) wsm[tid] = weights[b * SEQ + s0 + tid];
    __syncthreads();
    float ax = 0.f, ay = 0.f, az = 0.f, aw = 0.f;
    const float4* kp = (const float4*)(keys + (size_t)b * SEQ * HDIM + (size_t)s0 * HDIM) + tid;
    #pragma unroll 8
    for (int s = 0; s < 64; s++) {
        float4 kv = kp[s * 256];
        float wv = wsm[s];
        ax += wv * kv.x; ay += wv * kv.y; az += wv * kv.z; aw += wv * kv.w;
    }
    float* o = ctx + b * HDIM + tid * 4;
    atomicAdd(o + 0, ax);
    atomicAdd(o + 1, ay);
    atomicAdd(o + 2, az);
    atomicAdd(o + 3, aw);
}

extern "C" void kernel_launch(void* const* d_in, const int* in_sizes, int n_in,
                              void* d_out, int out_size, void* d_ws, size_t ws_size,
                              hipStream_t stream) {
    const float* query = (const float*)d_in[0];
    const float* keys  = (const float*)d_in[1];
    const float* Wa_w  = (const float*)d_in[2];
    const float* Wa_b  = (const float*)d_in[3];
    const float* Ua_w  = (const float*)d_in[4];
    const float* Ua_b  = (const float*)d_in[5];
    const float* Va_w  = (const float*)d_in[6];
    // Va_b unused: softmax is shift-invariant.
    float* out = (float*)d_out;   // [0, 32768) context, [32768, 98304) weights

    char* ws = (char*)d_ws;
    u16*  uab = (u16*)ws;                        // 2097152 B
    float* qb = (float*)(ws + 2097152);          //  131072 B
    float* sp = (float*)(ws + 2097152 + 131072); // 4194304 B

    cvt_kernel<<<(HDIM * HDIM) / 2048, 256, 0, stream>>>(Ua_w, uab);
    qb_kernel<<<dim3(BATCH, HDIM / 64), 256, 0, stream>>>(query, Wa_w, Wa_b, Ua_b, qb);
    gemm_score_kernel<<<dim3(HDIM / BN, M_TOTAL / BM), 256, 0, stream>>>(keys, uab, qb, Va_w, sp);
    softmax_kernel<<<BATCH, 256, 0, stream>>>(sp, out + BATCH * HDIM, out);
    context_kernel<<<dim3(BATCH, SEQ / 64), 256, 0, stream>>>(keys, out + BATCH * HDIM, out);
}